// Round 1
// baseline (333.586 us; speedup 1.0000x reference)
//
#include <hip/hip_runtime.h>

// Retrace loss: B=2048, T=512, D=16.
// One thread per (b,d) sequence; reverse scan over t; squared-error accumulate;
// wave reduce + one atomicAdd per 64-thread block into the scalar output.

constexpr int B = 2048;
constexpr int T = 512;
constexpr int D = 16;
constexpr float GAMMA = 0.99f;

__global__ __launch_bounds__(64) void retrace_kernel(
    const float* __restrict__ Q,
    const float* __restrict__ eQ,
    const float* __restrict__ tQ,
    const float* __restrict__ rw,
    const float* __restrict__ tpp,
    const float* __restrict__ bpp,
    float* __restrict__ out)
{
    const int tid = blockIdx.x * blockDim.x + threadIdx.x;  // 0..B*D-1
    const int b = tid >> 4;   // /D
    const int d = tid & 15;   // %D

    const size_t base = (size_t)b * T * D + d;
    const float* __restrict__ q_p = Q   + base;
    const float* __restrict__ e_p = eQ  + base;
    const float* __restrict__ t_p = tQ  + base;
    const float* __restrict__ r_p = rw  + base;
    const float* __restrict__ p_p = tpp + base;
    const float* __restrict__ b_p = bpp + (size_t)b * T;

    // carry init: target_Q[:, T-1]
    float carry = t_p[(size_t)(T - 1) * D];
    float acc = 0.0f;

    // Reverse scan: j = T-2 .. 0.
    // q_j = r[j] + GAMMA * (e[j+1] + c[j+1] * (carry - tq[j+1]))
    // c[t] = exp(min(tpp[t] - bpp[t], 0))
    // Addresses are independent of carry -> unroll lets the compiler batch
    // ~40 loads in flight per lane to hide HBM latency at low occupancy.
    #pragma unroll 8
    for (int j = T - 2; j >= 0; --j) {
        const float diff = p_p[(size_t)(j + 1) * D] - b_p[j + 1];
        const float cw   = __builtin_exp2f(fminf(diff, 0.0f) * 1.44269504088896340736f);
        const float tqv  = t_p[(size_t)(j + 1) * D];
        const float ev   = e_p[(size_t)(j + 1) * D];
        const float rv   = r_p[(size_t)j * D];
        const float qv   = q_p[(size_t)j * D];

        const float q = fmaf(GAMMA, fmaf(cw, carry - tqv, ev), rv);
        const float err = qv - q;
        acc = fmaf(err, err, acc);
        carry = q;
    }

    // Wave-level reduction (block = 64 threads = exactly one wave).
    #pragma unroll
    for (int off = 32; off > 0; off >>= 1)
        acc += __shfl_down(acc, off, 64);

    if (threadIdx.x == 0) {
        constexpr float inv_count = 1.0f / ((float)B * (float)(T - 1) * (float)D);
        atomicAdd(out, acc * inv_count);
    }
}

extern "C" void kernel_launch(void* const* d_in, const int* in_sizes, int n_in,
                              void* d_out, int out_size, void* d_ws, size_t ws_size,
                              hipStream_t stream) {
    const float* Q   = (const float*)d_in[0];
    const float* eQ  = (const float*)d_in[1];
    const float* tQ  = (const float*)d_in[2];
    const float* rw  = (const float*)d_in[3];
    const float* tpp = (const float*)d_in[4];
    const float* bpp = (const float*)d_in[5];
    float* out = (float*)d_out;

    // d_out is poisoned to 0xAA before every call; zero it (stream-ordered,
    // graph-capture safe) since we accumulate via atomics.
    hipMemsetAsync(out, 0, sizeof(float), stream);

    // 512 blocks x 64 threads = 32768 threads = one per (b,d); 2 waves/CU.
    retrace_kernel<<<dim3(512), dim3(64), 0, stream>>>(Q, eQ, tQ, rw, tpp, bpp, out);
}

// Round 2
// 320.044 us; speedup vs baseline: 1.0423x; 1.0423x over previous
//
#include <hip/hip_runtime.h>

// Retrace loss via chunked affine-scan decomposition.
// carry recurrence: carry_j = base_j + (GAMMA*c_{j+1}) * carry_{j+1}  (affine)
// Per chunk, represent carry symbolically as alpha + beta*c (c = carry entering
// chunk from the right) and the chunk's loss as a quadratic P - 2Sc + Wc^2.
// Phase 1: all (b, d, chunk) in parallel, one read pass over the data.
// Phase 2: tiny sequential chain over 16 chunk summaries per sequence.

constexpr int B = 2048;
constexpr int T = 512;
constexpr int D = 16;
constexpr int NC = 16;            // number of time chunks
constexpr int CS = 32;            // chunk size in scan steps (last chunk: 31)
constexpr int SQ = B * (D / 4);   // 8192 sequence-quads (float4 over d)
constexpr float GAMMA = 0.99f;
constexpr float LOG2E = 1.44269504088896340736f;

__global__ __launch_bounds__(256) void retrace_phase1(
    const float* __restrict__ Q,
    const float* __restrict__ eQ,
    const float* __restrict__ tQ,
    const float* __restrict__ rw,
    const float* __restrict__ tpp,
    const float* __restrict__ bpp,
    float4* __restrict__ ws)
{
    const int s  = blockIdx.x * blockDim.x + threadIdx.x;  // 0..SQ-1
    const int k  = blockIdx.y;                             // chunk id
    const int b  = s >> 2;
    const int dq = s & 3;

    const int j_start = k * CS;
    const int j_end   = min(j_start + CS, T - 1);  // scan steps j in [j_start, j_end)

    // float4 views: element (b, t, dq) at index ((b*T + t)*4 + dq)
    const float4* __restrict__ q4 = (const float4*)Q;
    const float4* __restrict__ e4 = (const float4*)eQ;
    const float4* __restrict__ t4 = (const float4*)tQ;
    const float4* __restrict__ r4 = (const float4*)rw;
    const float4* __restrict__ p4 = (const float4*)tpp;
    const size_t row = (size_t)b * T * 4 + dq;
    const float* __restrict__ b_p = bpp + (size_t)b * T;

    float alpha[4] = {0.f, 0.f, 0.f, 0.f};
    float beta[4]  = {1.f, 1.f, 1.f, 1.f};
    float P[4] = {0.f, 0.f, 0.f, 0.f};
    float S[4] = {0.f, 0.f, 0.f, 0.f};
    float W[4] = {0.f, 0.f, 0.f, 0.f};

    #pragma unroll 4
    for (int j = j_end - 1; j >= j_start; --j) {
        const float4 tp4 = p4[row + (size_t)(j + 1) * 4];
        const float4 tq4 = t4[row + (size_t)(j + 1) * 4];
        const float4 ee4 = e4[row + (size_t)(j + 1) * 4];
        const float4 rr4 = r4[row + (size_t)j * 4];
        const float4 qq4 = q4[row + (size_t)j * 4];
        const float  bp  = b_p[j + 1];

        const float* tp = (const float*)&tp4;
        const float* tq = (const float*)&tq4;
        const float* ee = (const float*)&ee4;
        const float* rr = (const float*)&rr4;
        const float* qq = (const float*)&qq4;

        #pragma unroll
        for (int i = 0; i < 4; ++i) {
            const float cw = __builtin_exp2f(fminf(tp[i] - bp, 0.f) * LOG2E);
            const float g  = GAMMA * cw;
            // base = r + GAMMA*e - g*tq
            const float base = fmaf(-g, tq[i], fmaf(GAMMA, ee[i], rr[i]));
            alpha[i] = fmaf(g, alpha[i], base);
            beta[i]  = g * beta[i];
            const float u = qq[i] - alpha[i];
            P[i] = fmaf(u, u, P[i]);
            S[i] = fmaf(u, beta[i], S[i]);
            W[i] = fmaf(beta[i], beta[i], W[i]);
        }
    }

    const size_t o = (size_t)k * SQ + s;
    float4* wsA = ws;
    float4* wsM = ws + (size_t)NC * SQ;
    float4* wsP = ws + (size_t)2 * NC * SQ;
    float4* wsS = ws + (size_t)3 * NC * SQ;
    float4* wsW = ws + (size_t)4 * NC * SQ;
    wsA[o] = *(const float4*)alpha;
    wsM[o] = *(const float4*)beta;
    wsP[o] = *(const float4*)P;
    wsS[o] = *(const float4*)S;
    wsW[o] = *(const float4*)W;
}

__global__ __launch_bounds__(64) void retrace_phase2(
    const float* __restrict__ tQ,
    const float4* __restrict__ ws,
    float* __restrict__ out)
{
    const int s  = blockIdx.x * blockDim.x + threadIdx.x;  // 0..SQ-1
    const int b  = s >> 2;
    const int dq = s & 3;

    const float4* wsA = ws;
    const float4* wsM = ws + (size_t)NC * SQ;
    const float4* wsP = ws + (size_t)2 * NC * SQ;
    const float4* wsS = ws + (size_t)3 * NC * SQ;
    const float4* wsW = ws + (size_t)4 * NC * SQ;

    // c = carry entering from the right of the last chunk = target_Q[b, T-1, :]
    float4 c4 = ((const float4*)tQ)[((size_t)b * T + (T - 1)) * 4 + dq];
    float* c = (float*)&c4;
    float loss[4] = {0.f, 0.f, 0.f, 0.f};

    for (int k = NC - 1; k >= 0; --k) {
        const size_t o = (size_t)k * SQ + s;
        const float4 A4 = wsA[o], M4 = wsM[o], P4 = wsP[o], S4 = wsS[o], W4 = wsW[o];
        const float* A = (const float*)&A4;
        const float* M = (const float*)&M4;
        const float* P = (const float*)&P4;
        const float* S = (const float*)&S4;
        const float* W = (const float*)&W4;
        #pragma unroll
        for (int i = 0; i < 4; ++i) {
            // loss += P - 2*S*c + W*c^2
            loss[i] += fmaf(c[i], fmaf(W[i], c[i], -2.f * S[i]), P[i]);
            // carry at chunk start = A + M*c
            c[i] = fmaf(M[i], c[i], A[i]);
        }
    }

    float acc = (loss[0] + loss[1]) + (loss[2] + loss[3]);
    #pragma unroll
    for (int off = 32; off > 0; off >>= 1)
        acc += __shfl_down(acc, off, 64);

    if (threadIdx.x == 0) {
        constexpr float inv_count = 1.0f / ((float)B * (float)(T - 1) * (float)D);
        atomicAdd(out, acc * inv_count);
    }
}

extern "C" void kernel_launch(void* const* d_in, const int* in_sizes, int n_in,
                              void* d_out, int out_size, void* d_ws, size_t ws_size,
                              hipStream_t stream) {
    const float* Q   = (const float*)d_in[0];
    const float* eQ  = (const float*)d_in[1];
    const float* tQ  = (const float*)d_in[2];
    const float* rw  = (const float*)d_in[3];
    const float* tpp = (const float*)d_in[4];
    const float* bpp = (const float*)d_in[5];
    float* out = (float*)d_out;
    float4* ws = (float4*)d_ws;   // needs 5*NC*SQ*16 B = 10.5 MB

    hipMemsetAsync(out, 0, sizeof(float), stream);

    // Phase 1: 512 blocks x 256 = 2048 waves = 8 waves/CU
    retrace_phase1<<<dim3(SQ / 256, NC), dim3(256), 0, stream>>>(
        Q, eQ, tQ, rw, tpp, bpp, ws);

    // Phase 2: 8192 threads, chains 16 chunk summaries per sequence
    retrace_phase2<<<dim3(SQ / 64), dim3(64), 0, stream>>>(tQ, ws, out);
}

// Round 3
// 317.963 us; speedup vs baseline: 1.0491x; 1.0065x over previous
//
#include <hip/hip_runtime.h>

// Retrace loss via chunked affine-scan decomposition + explicit register
// software pipelining.
// carry recurrence: carry_j = base_j + (GAMMA*c_{j+1}) * carry_{j+1}  (affine)
// Per chunk: carry = alpha + beta*c, loss = P - 2Sc + Wc^2 (c = incoming carry).
// Phase 1: one thread per (b, d-quad, chunk); depth-4 rotating load buffers so
//          ~20 float4 loads stay in flight per wave (round-2 showed the
//          compiler won't pipeline on its own: VGPR=36, 2.2 TB/s, latency-bound).
// Phase 2: tiny sequential chain over 16 chunk summaries per sequence.

constexpr int B = 2048;
constexpr int T = 512;
constexpr int D = 16;
constexpr int NC = 16;            // time chunks
constexpr int CS = 32;            // scan steps per chunk (last chunk: 31)
constexpr int SQ = B * (D / 4);   // 8192 sequence-quads
constexpr int PF = 4;             // prefetch depth (iterations in flight)
constexpr float GAMMA = 0.99f;
constexpr float LOG2E = 1.44269504088896340736f;

template <int STEPS>
__device__ __forceinline__ void chunk_scan(
    const float4* __restrict__ q4, const float4* __restrict__ e4,
    const float4* __restrict__ t4, const float4* __restrict__ r4,
    const float4* __restrict__ p4, const float* __restrict__ b_p,
    const int j_hi,              // first (highest) scan step; j decreases
    float* __restrict__ alpha, float* __restrict__ beta,
    float* __restrict__ P, float* __restrict__ S, float* __restrict__ W)
{
    // Rotating register buffers; slot = i % PF. Fully unrolled (STEPS is a
    // compile-time constant) so all indexing is static -> registers, and the
    // backend can keep PF iterations' loads outstanding (vmcnt(k), k>0).
    float4 tpB[PF], tqB[PF], eeB[PF], rrB[PF], qqB[PF];
    float  bpB[PF];

    #pragma unroll
    for (int p = 0; p < PF; ++p) {
        const int j = j_hi - p;
        tpB[p] = p4[(size_t)(j + 1) * 4];
        tqB[p] = t4[(size_t)(j + 1) * 4];
        eeB[p] = e4[(size_t)(j + 1) * 4];
        rrB[p] = r4[(size_t)j * 4];
        qqB[p] = q4[(size_t)j * 4];
        bpB[p] = b_p[j + 1];
    }

    #pragma unroll
    for (int i = 0; i < STEPS; ++i) {
        const int slot = i % PF;
        const float4 tp4 = tpB[slot];
        const float4 tq4 = tqB[slot];
        const float4 ee4 = eeB[slot];
        const float4 rr4 = rrB[slot];
        const float4 qq4 = qqB[slot];
        const float  bp  = bpB[slot];

        if (i + PF < STEPS) {               // compile-time condition
            const int j = j_hi - (i + PF);
            tpB[slot] = p4[(size_t)(j + 1) * 4];
            tqB[slot] = t4[(size_t)(j + 1) * 4];
            eeB[slot] = e4[(size_t)(j + 1) * 4];
            rrB[slot] = r4[(size_t)j * 4];
            qqB[slot] = q4[(size_t)j * 4];
            bpB[slot] = b_p[j + 1];
        }

        const float* tp = (const float*)&tp4;
        const float* tq = (const float*)&tq4;
        const float* ee = (const float*)&ee4;
        const float* rr = (const float*)&rr4;
        const float* qq = (const float*)&qq4;

        #pragma unroll
        for (int ii = 0; ii < 4; ++ii) {
            const float cw = __builtin_exp2f(fminf(tp[ii] - bp, 0.f) * LOG2E);
            const float g  = GAMMA * cw;
            const float base = fmaf(-g, tq[ii], fmaf(GAMMA, ee[ii], rr[ii]));
            alpha[ii] = fmaf(g, alpha[ii], base);
            beta[ii]  = g * beta[ii];
            const float u = qq[ii] - alpha[ii];
            P[ii] = fmaf(u, u, P[ii]);
            S[ii] = fmaf(u, beta[ii], S[ii]);
            W[ii] = fmaf(beta[ii], beta[ii], W[ii]);
        }
    }
}

__global__ __launch_bounds__(256) void retrace_phase1(
    const float* __restrict__ Q,
    const float* __restrict__ eQ,
    const float* __restrict__ tQ,
    const float* __restrict__ rw,
    const float* __restrict__ tpp,
    const float* __restrict__ bpp,
    float4* __restrict__ ws)
{
    const int s  = blockIdx.x * blockDim.x + threadIdx.x;  // 0..SQ-1
    const int k  = blockIdx.y;                             // chunk id
    const int b  = s >> 2;
    const int dq = s & 3;

    const size_t row = (size_t)b * T * 4 + dq;             // float4 units
    const float4* q4 = (const float4*)Q   + row;
    const float4* e4 = (const float4*)eQ  + row;
    const float4* t4 = (const float4*)tQ  + row;
    const float4* r4 = (const float4*)rw  + row;
    const float4* p4 = (const float4*)tpp + row;
    const float*  b_p = bpp + (size_t)b * T;

    float alpha[4] = {0.f, 0.f, 0.f, 0.f};
    float beta[4]  = {1.f, 1.f, 1.f, 1.f};
    float P[4] = {0.f, 0.f, 0.f, 0.f};
    float S[4] = {0.f, 0.f, 0.f, 0.f};
    float W[4] = {0.f, 0.f, 0.f, 0.f};

    if (k == NC - 1) {
        // last chunk: j in [480, 510], 31 steps
        chunk_scan<CS - 1>(q4, e4, t4, r4, p4, b_p, T - 2 - 1, alpha, beta, P, S, W);
    } else {
        // j in [k*CS, (k+1)*CS - 1], 32 steps
        chunk_scan<CS>(q4, e4, t4, r4, p4, b_p, (k + 1) * CS - 1, alpha, beta, P, S, W);
    }

    const size_t o = (size_t)k * SQ + s;
    float4* wsA = ws;
    float4* wsM = ws + (size_t)NC * SQ;
    float4* wsP = ws + (size_t)2 * NC * SQ;
    float4* wsS = ws + (size_t)3 * NC * SQ;
    float4* wsW = ws + (size_t)4 * NC * SQ;
    wsA[o] = *(const float4*)alpha;
    wsM[o] = *(const float4*)beta;
    wsP[o] = *(const float4*)P;
    wsS[o] = *(const float4*)S;
    wsW[o] = *(const float4*)W;
}

__global__ __launch_bounds__(64) void retrace_phase2(
    const float* __restrict__ tQ,
    const float4* __restrict__ ws,
    float* __restrict__ out)
{
    const int s  = blockIdx.x * blockDim.x + threadIdx.x;  // 0..SQ-1
    const int b  = s >> 2;
    const int dq = s & 3;

    const float4* wsA = ws;
    const float4* wsM = ws + (size_t)NC * SQ;
    const float4* wsP = ws + (size_t)2 * NC * SQ;
    const float4* wsS = ws + (size_t)3 * NC * SQ;
    const float4* wsW = ws + (size_t)4 * NC * SQ;

    float4 c4 = ((const float4*)tQ)[((size_t)b * T + (T - 1)) * 4 + dq];
    float* c = (float*)&c4;
    float loss[4] = {0.f, 0.f, 0.f, 0.f};

    #pragma unroll
    for (int k = NC - 1; k >= 0; --k) {
        const size_t o = (size_t)k * SQ + s;
        const float4 A4 = wsA[o], M4 = wsM[o], P4 = wsP[o], S4 = wsS[o], W4 = wsW[o];
        const float* A = (const float*)&A4;
        const float* M = (const float*)&M4;
        const float* P = (const float*)&P4;
        const float* S = (const float*)&S4;
        const float* W = (const float*)&W4;
        #pragma unroll
        for (int i = 0; i < 4; ++i) {
            loss[i] += fmaf(c[i], fmaf(W[i], c[i], -2.f * S[i]), P[i]);
            c[i] = fmaf(M[i], c[i], A[i]);
        }
    }

    float acc = (loss[0] + loss[1]) + (loss[2] + loss[3]);
    #pragma unroll
    for (int off = 32; off > 0; off >>= 1)
        acc += __shfl_down(acc, off, 64);

    if (threadIdx.x == 0) {
        constexpr float inv_count = 1.0f / ((float)B * (float)(T - 1) * (float)D);
        atomicAdd(out, acc * inv_count);
    }
}

extern "C" void kernel_launch(void* const* d_in, const int* in_sizes, int n_in,
                              void* d_out, int out_size, void* d_ws, size_t ws_size,
                              hipStream_t stream) {
    const float* Q   = (const float*)d_in[0];
    const float* eQ  = (const float*)d_in[1];
    const float* tQ  = (const float*)d_in[2];
    const float* rw  = (const float*)d_in[3];
    const float* tpp = (const float*)d_in[4];
    const float* bpp = (const float*)d_in[5];
    float* out = (float*)d_out;
    float4* ws = (float4*)d_ws;   // 5*NC*SQ*16 B = 10.5 MB

    hipMemsetAsync(out, 0, sizeof(float), stream);

    retrace_phase1<<<dim3(SQ / 256, NC), dim3(256), 0, stream>>>(
        Q, eQ, tQ, rw, tpp, bpp, ws);

    retrace_phase2<<<dim3(SQ / 64), dim3(64), 0, stream>>>(tQ, ws, out);
}

// Round 4
// 305.510 us; speedup vs baseline: 1.0919x; 1.0408x over previous
//
#include <hip/hip_runtime.h>

// Retrace loss, chunked affine-scan + LDS-staged coalesced loads.
//
// Rounds 1-3 post-mortem: scattered 64 B segments per wave-load pin effective
// memory throughput at ~8 B/cyc/CU regardless of occupancy (R2) or per-wave
// ILP (R3, VGPR 36->92, no change). Fix: stage via LDS with fully-contiguous
// 1 KB-per-instruction global_load_lds (width 16), then feed the scan from LDS.
//
// Decomposition (unchanged): carry_j = base_j + g_j*carry_{j+1} is affine, so
// per chunk carry = alpha + beta*c and chunk loss = P - 2Sc + Wc^2 in the
// incoming carry c. Phase 2 chains 16 chunk summaries per (b,d).

constexpr int B  = 2048;
constexpr int T  = 512;
constexpr int D  = 16;
constexpr int NC = 16;             // time chunks
constexpr int CS = 32;             // scan steps per chunk (last chunk: 31)
constexpr int BPB = 4;             // b-values per block
constexpr int ROWS = CS + 1;       // staged t-rows per chunk (last chunk: 32)
constexpr int SQ = B * (D / 4);    // 8192 sequence-quads (ws layout unit)
constexpr float GAMMA = 0.99f;
constexpr float LOG2E = 1.44269504088896340736f;

constexpr int SEG = ROWS * D;      // 528 floats per (array, b): 2112 B
constexpr int ARR = BPB * SEG;     // 2112 floats per array
constexpr int LDS_FLOATS = 5 * ARR + BPB * ROWS;  // + bpp rows

__device__ __forceinline__ void load_lds16(const float* g, float* l) {
    __builtin_amdgcn_global_load_lds(
        (const __attribute__((address_space(1))) unsigned int*)g,
        (__attribute__((address_space(3))) unsigned int*)l, 16, 0, 0);
}
__device__ __forceinline__ void load_lds4(const float* g, float* l) {
    __builtin_amdgcn_global_load_lds(
        (const __attribute__((address_space(1))) unsigned int*)g,
        (__attribute__((address_space(3))) unsigned int*)l, 4, 0, 0);
}

__global__ __launch_bounds__(64) void retrace_phase1(
    const float* __restrict__ Q,
    const float* __restrict__ eQ,
    const float* __restrict__ tQ,
    const float* __restrict__ rw,
    const float* __restrict__ tpp,
    const float* __restrict__ bpp,
    float* __restrict__ ws)
{
    __shared__ float lds[LDS_FLOATS];

    const int tid = threadIdx.x;           // 0..63
    const int k   = blockIdx.y;            // chunk
    const int b0  = blockIdx.x * BPB;
    const int t0  = k * CS;

    const bool last = (k == NC - 1);
    const int rows = last ? CS : ROWS;     // 32 or 33 (t0+32 would be OOB at k=15)
    const int n4   = rows * D / 4;         // 128 or 132 float4 per (array, b)

    // ---- Stage: direct global->LDS, 1 KB contiguous per instruction ----
    const float* gbase[5] = {Q, eQ, tQ, rw, tpp};
    #pragma unroll
    for (int a = 0; a < 5; ++a) {
        #pragma unroll
        for (int bl = 0; bl < BPB; ++bl) {
            const float* g = gbase[a] + ((size_t)(b0 + bl) * T + t0) * D;
            float* l = lds + a * ARR + bl * SEG;
            for (int off = tid; off < n4; off += 64)
                load_lds16(g + (size_t)off * 4, l + (size_t)off * 4);
        }
    }
    #pragma unroll
    for (int bl = 0; bl < BPB; ++bl) {
        const float* g = bpp + (size_t)(b0 + bl) * T + t0;
        float* l = lds + 5 * ARR + bl * ROWS;
        if (tid < rows) load_lds4(g + tid, l + tid);
    }
    __syncthreads();   // drains vmcnt for global_load_lds

    // ---- Scan from LDS: thread (bl, d), descending j over the chunk ----
    const int bl = tid >> 4;
    const int d  = tid & 15;
    const float* lQ = lds + 0 * ARR + bl * SEG + d;
    const float* lE = lds + 1 * ARR + bl * SEG + d;
    const float* lT = lds + 2 * ARR + bl * SEG + d;
    const float* lR = lds + 3 * ARR + bl * SEG + d;
    const float* lP = lds + 4 * ARR + bl * SEG + d;
    const float* lB = lds + 5 * ARR + bl * ROWS;

    const int steps = last ? (CS - 1) : CS;  // k=15: j in [480,510], 31 steps

    float alpha = 0.f, beta = 1.f, P = 0.f, S = 0.f, W = 0.f;
    #pragma unroll 8
    for (int i = steps - 1; i >= 0; --i) {
        const float tp = lP[(i + 1) * D];
        const float tq = lT[(i + 1) * D];
        const float ev = lE[(i + 1) * D];
        const float rv = lR[i * D];
        const float qv = lQ[i * D];
        const float bp = lB[i + 1];

        const float cw = __builtin_exp2f(fminf(tp - bp, 0.f) * LOG2E);
        const float g  = GAMMA * cw;
        const float base = fmaf(-g, tq, fmaf(GAMMA, ev, rv));
        alpha = fmaf(g, alpha, base);
        beta  = g * beta;
        const float u = qv - alpha;
        P = fmaf(u, u, P);
        S = fmaf(u, beta, S);
        W = fmaf(beta, beta, W);
    }

    // ---- Store chunk summary: 64 consecutive floats per (k, b-group) ----
    // ws float4 layout per sub-array: index (k*SQ + b*4 + dq), lane d%4.
    // Flattened: float index (k*SQ + b0*4)*4 + tid  with tid = bl*16 + d.
    const size_t AS = (size_t)NC * SQ * 4;          // floats per ws sub-array
    const size_t o  = ((size_t)k * SQ + (size_t)b0 * 4) * 4 + tid;
    ws[0 * AS + o] = alpha;
    ws[1 * AS + o] = beta;
    ws[2 * AS + o] = P;
    ws[3 * AS + o] = S;
    ws[4 * AS + o] = W;
}

__global__ __launch_bounds__(64) void retrace_phase2(
    const float* __restrict__ tQ,
    const float4* __restrict__ ws,
    float* __restrict__ out)
{
    const int s  = blockIdx.x * blockDim.x + threadIdx.x;  // 0..SQ-1
    const int b  = s >> 2;
    const int dq = s & 3;

    const float4* wsA = ws;
    const float4* wsM = ws + (size_t)NC * SQ;
    const float4* wsP = ws + (size_t)2 * NC * SQ;
    const float4* wsS = ws + (size_t)3 * NC * SQ;
    const float4* wsW = ws + (size_t)4 * NC * SQ;

    float4 c4 = ((const float4*)tQ)[((size_t)b * T + (T - 1)) * 4 + dq];
    float* c = (float*)&c4;
    float loss[4] = {0.f, 0.f, 0.f, 0.f};

    #pragma unroll
    for (int k = NC - 1; k >= 0; --k) {
        const size_t o = (size_t)k * SQ + s;
        const float4 A4 = wsA[o], M4 = wsM[o], P4 = wsP[o], S4 = wsS[o], W4 = wsW[o];
        const float* A = (const float*)&A4;
        const float* M = (const float*)&M4;
        const float* P = (const float*)&P4;
        const float* S = (const float*)&S4;
        const float* W = (const float*)&W4;
        #pragma unroll
        for (int i = 0; i < 4; ++i) {
            loss[i] += fmaf(c[i], fmaf(W[i], c[i], -2.f * S[i]), P[i]);
            c[i] = fmaf(M[i], c[i], A[i]);
        }
    }

    float acc = (loss[0] + loss[1]) + (loss[2] + loss[3]);
    #pragma unroll
    for (int off = 32; off > 0; off >>= 1)
        acc += __shfl_down(acc, off, 64);

    if (threadIdx.x == 0) {
        constexpr float inv_count = 1.0f / ((float)B * (float)(T - 1) * (float)D);
        atomicAdd(out, acc * inv_count);
    }
}

extern "C" void kernel_launch(void* const* d_in, const int* in_sizes, int n_in,
                              void* d_out, int out_size, void* d_ws, size_t ws_size,
                              hipStream_t stream) {
    const float* Q   = (const float*)d_in[0];
    const float* eQ  = (const float*)d_in[1];
    const float* tQ  = (const float*)d_in[2];
    const float* rw  = (const float*)d_in[3];
    const float* tpp = (const float*)d_in[4];
    const float* bpp = (const float*)d_in[5];
    float* out = (float*)d_out;
    float* ws = (float*)d_ws;   // 5 * NC * SQ * 16 B = 10.5 MB

    hipMemsetAsync(out, 0, sizeof(float), stream);

    // Phase 1: 512 x 16 single-wave blocks; LDS 42.8 KB -> 3 blocks/CU.
    retrace_phase1<<<dim3(B / BPB, NC), dim3(64), 0, stream>>>(
        Q, eQ, tQ, rw, tpp, bpp, ws);

    // Phase 2: chains 16 chunk summaries per sequence.
    retrace_phase2<<<dim3(SQ / 64), dim3(64), 0, stream>>>(tQ, (const float4*)ws, out);
}